// Round 4
// baseline (270.566 us; speedup 1.0000x reference)
//
#include <hip/hip_runtime.h>
#include <hip/hip_bf16.h>

// Causal linear attention, fused single kernel with flag-based chunk handshake.
// B=4 H=16 T=2048 D=64. Chunk C=256, NC=8, BH=64. Grid 512 blocks x 512 thr
// (= exactly 2 blocks/CU co-residency capacity, forced by launch_bounds:
//  VGPR<=128, LDS 63KB -> 126KB/CU of 160KB, 16 waves/CU of 32).
//
// Phase 1: block (bh,c) computes KV_c = K_c^T V_c -> ws, then publishes a
//   per-chunk flag (block barrier -> agent-scope RELEASE store). Phase 1 has
//   NO dependencies -> producers never wait -> no deadlock given residency.
// Phase 2: prefix consumers ACQUIRE-poll the needed flags (each thread polls
//   for itself -> its own subsequent state loads are correctly ordered /
//   caches invalidated), then O = Q @ prefixKV + tril(Q K_c^T) V_c.
//
// vs R3 (cooperative launch, never executed): regular capturable launch.
// Flags live at ws+8MiB and are zeroed each iteration by a hipMemsetAsync
// node (poison-proof). XCD swizzle: all 8 chunks of a bh on one XCD so ws
// states + flags stay L2-local.

#define B_   4
#define H_   16
#define T_   2048
#define D_   64
#define BH_  64
#define CCH  256
#define NCH  8
#define LPAD 8
#define LW   (D_ + LPAD)   // 72 bf16 = 144 B row stride

#define FLAG_OFF_BYTES (8u << 20)  // ws: [0,8MiB) = 512 KV states, then flags

typedef __bf16 bf16x4 __attribute__((ext_vector_type(4)));
typedef __bf16 bf16x8 __attribute__((ext_vector_type(8)));
typedef float  f32x2  __attribute__((ext_vector_type(2)));
typedef float  f32x4  __attribute__((ext_vector_type(4)));

// MFMA 16x16x32 bf16 fragment layouts (HW-verified):
//   A: A[m = lane&15][k = (lane>>4)*8 + j]   (8 contiguous k per lane)
//   B: B[k = (lane>>4)*8 + j][n = lane&15]
//   C/D: row = (lane>>4)*4 + reg, col = lane&15
// Mirror property: row-major 8-elem load of X rows = A-frag(X) = B-frag(X^T).

__global__ __launch_bounds__(512, 4) void fused_attn_kernel(
    const float* __restrict__ q, const float* __restrict__ k,
    const float* __restrict__ v, float* __restrict__ kvws,
    int* __restrict__ flags, float* __restrict__ out) {
  __shared__ __align__(16) __bf16 KVT[D_][LW];     // KVsum^T [d2][d1]
  __shared__ __align__(16) __bf16 Kj[2][64][LW];   // ph2: K [s][d]; ph1: K^T [d][s]
  __shared__ __align__(16) __bf16 VTj[2][64][LW];  // V^T [d][s] (both phases)
  __shared__ __align__(16) __bf16 Sw[8][16][LW];   // per-wave S tile
  // 9216 + 18432 + 18432 + 18432 = 64512 B -> 2 blocks/CU

  const int tid  = threadIdx.x;
  const int lane = tid & 63;
  const int w    = tid >> 6;        // 0..7
  const int quad = lane >> 4;
  const int l15  = lane & 15;
  // XCD swizzle (perf-only): XCD = blockIdx%8 -> pin all 8 chunks of a bh to
  // one XCD so its ws states + flags are L2-local. Bijective on [0,512).
  const int bx  = blockIdx.x;
  const int bh  = (bx & 7) * 8 + ((bx >> 3) & 7);
  const int c   = bx >> 6;
  const int lin = bh * NCH + c;     // logical state index
  const long base = ((long)bh * T_ + (long)c * CCH) * D_;

  const f32x4 vzero = {0.f, 0.f, 0.f, 0.f};

  // ================= phase 1: KV_c = K_c^T V_c =================
  // staging: waves 0-3 stage K, waves 4-7 stage V (4x4 register transpose)
  const int tt  = tid & 255;
  const int s4a = tt >> 4;    // s-block of 4
  const int d4a = tt & 15;    // d-block of 4
  const int mat = tid >> 8;   // 0 = K, 1 = V (wave-uniform)
  const float* src1 = mat ? v : k;
  __bf16* dst1 = mat ? &VTj[0][0][0] : &Kj[0][0][0];
  const float* sp1 = src1 + base + (long)(s4a * 4) * D_ + d4a * 4;

  f32x4 reg1[4];
  auto LOAD1 = [&](int st) {
#pragma unroll
    for (int r = 0; r < 4; ++r)
      reg1[r] = *(const f32x4*)(sp1 + (long)(st * 64 + r) * D_);
  };
  auto WRITE1 = [&](int p) {
#pragma unroll
    for (int cc2 = 0; cc2 < 4; ++cc2) {
      bf16x4 a;
#pragma unroll
      for (int r = 0; r < 4; ++r) a[r] = (__bf16)reg1[r][cc2];
      *(bf16x4*)(dst1 + ((long)p * 64 + d4a * 4 + cc2) * LW + s4a * 4) = a;
    }
  };

  // phase-2 staging mappings + lambdas (also used for pre-wait j=0 prefetch)
  const int slK = tid >> 3;          // K: row 0..63
  const int d0K = (tid & 7) * 8;     // K: 8 cols
  const int sV  = (tid >> 5) * 4;    // V: s-block of 4
  const int dV  = (tid & 31) * 2;    // V: 2 cols

  f32x4 kreg0, kreg1;
  f32x2 vreg[4];
  auto LOADJ = [&](int j) {
    const float* kp = k + base + (long)(j * 64 + slK) * D_ + d0K;
    const float* vp = v + base + (long)(j * 64 + sV) * D_ + dV;
    kreg0 = *(const f32x4*)(kp);
    kreg1 = *(const f32x4*)(kp + 4);
#pragma unroll
    for (int r = 0; r < 4; ++r) vreg[r] = *(const f32x2*)(vp + (long)r * D_);
  };
  auto WRITEJ = [&](int p) {
    bf16x8 kb;
#pragma unroll
    for (int e = 0; e < 4; ++e) {
      kb[e]     = (__bf16)kreg0[e];
      kb[4 + e] = (__bf16)kreg1[e];
    }
    *(bf16x8*)&Kj[p][slK][d0K] = kb;
#pragma unroll
    for (int e = 0; e < 2; ++e) {
      bf16x4 va;
#pragma unroll
      for (int r = 0; r < 4; ++r) va[r] = (__bf16)vreg[r][e];
      *(bf16x4*)&VTj[p][dV + e][sV] = va;
    }
  };

  LOAD1(0);
  WRITE1(0);

  // Q A-fragments (issued early; consumed in phase 2).
  // wave w owns M-tiles {w, 15-w}: uniform 5 (j,tile) MFMA pairs per wave.
  bf16x8 qf[2][2];
#pragma unroll
  for (int t = 0; t < 2; ++t) {
    const int m = t ? (15 - w) : w;
    const float* qp = q + base + (long)(m * 16 + l15) * D_ + quad * 8;
#pragma unroll
    for (int ks = 0; ks < 2; ++ks) {
      f32x4 lo = *(const f32x4*)(qp + ks * 32);
      f32x4 hi = *(const f32x4*)(qp + ks * 32 + 4);
      bf16x8 f;
#pragma unroll
      for (int e = 0; e < 4; ++e) {
        f[e]     = (__bf16)lo[e];
        f[4 + e] = (__bf16)hi[e];
      }
      qf[t][ks] = f;
    }
  }

  __syncthreads();

  // phase-1 MFMA: wave w -> d1 rows (w&3)*16..+16, d2 cols (w>>2)*32..+32
  const int r1 = (w & 3) * 16;
  const int nb = (w >> 2) * 2;
  f32x4 acc1[2] = {vzero, vzero};
  for (int st = 0; st < 4; ++st) {
    const int p = st & 1;
    if (st < 3) LOAD1(st + 1);  // issue early
#pragma unroll
    for (int ks = 0; ks < 2; ++ks) {
      bf16x8 a = *(const bf16x8*)&Kj[p][r1 + l15][ks * 32 + quad * 8];  // K^T rows
#pragma unroll
      for (int nn = 0; nn < 2; ++nn) {
        bf16x8 b = *(const bf16x8*)&VTj[p][(nb + nn) * 16 + l15][ks * 32 + quad * 8];
        acc1[nn] = __builtin_amdgcn_mfma_f32_16x16x32_bf16(a, b, acc1[nn], 0, 0, 0);
      }
    }
    if (st < 3) {
      WRITE1(p ^ 1);
      __syncthreads();
    }
  }
  // write own chunk state. C layout: d1 = r1+quad*4+rr, d2 = col.
  {
    float* wsp = kvws + ((long)lin << 12);
#pragma unroll
    for (int nn = 0; nn < 2; ++nn)
#pragma unroll
      for (int rr = 0; rr < 4; ++rr)
        wsp[(r1 + quad * 4 + rr) * 64 + (nb + nn) * 16 + l15] = acc1[nn][rr];
  }
  // publish: all threads' ws stores are drained by the barrier (compiler emits
  // vmcnt(0) before s_barrier); agent-scope release then writes back L2 before
  // the flag store becomes visible.
  __syncthreads();
  if (tid == 0)
    __hip_atomic_store(&flags[lin], 1, __ATOMIC_RELEASE, __HIP_MEMORY_SCOPE_AGENT);

  // prefetch phase-2 j=0 tile into region 0 (phase-1 st=3 readers use region
  // 1 -> disjoint; publish barrier already passed).
  LOADJ(0);
  WRITEJ(0);

  // ================= phase 2: attention =================
  // ---- prefix-sum KV states of prior chunks -> KVT (bf16, transposed).
  // Each thread acquire-polls the flag itself so its own state loads are
  // ordered (cache-invalidated) after the acquire.
  float kvacc[8];
#pragma unroll
  for (int i = 0; i < 8; ++i) kvacc[i] = 0.f;
  const float* wsbh = kvws + ((long)(bh * NCH) << 12);
  for (int cc = 0; cc < c; ++cc) {
    while (__hip_atomic_load(&flags[bh * NCH + cc], __ATOMIC_ACQUIRE,
                             __HIP_MEMORY_SCOPE_AGENT) == 0)
      __builtin_amdgcn_s_sleep(2);
    const float* pp = wsbh + ((long)cc << 12) + tid * 8;
#pragma unroll
    for (int x = 0; x < 2; ++x) {
      f32x4 t2 = *(const f32x4*)(pp + x * 4);
#pragma unroll
      for (int e = 0; e < 4; ++e) kvacc[x * 4 + e] += t2[e];
    }
  }
  {
    const int d1  = tid >> 3;          // lin8 = tid*8+ii: d1 = lin8>>6
    const int d2b = (tid & 7) * 8;     //                  d2 = d2b+ii
#pragma unroll
    for (int ii = 0; ii < 8; ++ii) KVT[d2b + ii][d1] = (__bf16)kvacc[ii];
  }

  f32x4 acc[2][4];
#pragma unroll
  for (int t = 0; t < 2; ++t)
#pragma unroll
    for (int n = 0; n < 4; ++n) acc[t][n] = vzero;

  LOADJ(1);         // prefetch j=1 under the inter-chunk matmul
  __syncthreads();  // KVT + j=0 tile ready

  // ---- inter-chunk: O += Q @ KVsum (zeros when c==0; uniform work)
#pragma unroll
  for (int ks = 0; ks < 2; ++ks)
#pragma unroll
    for (int n = 0; n < 4; ++n) {
      bf16x8 b = *(const bf16x8*)&KVT[n * 16 + l15][ks * 32 + quad * 8];
#pragma unroll
      for (int t = 0; t < 2; ++t)
        acc[t][n] =
            __builtin_amdgcn_mfma_f32_16x16x32_bf16(qf[t][ks], b, acc[t][n], 0, 0, 0);
    }

  // ---- intra-chunk causal part over 4 key subtiles of 64
  for (int j = 0; j < 4; ++j) {
    const int p = j & 1;
    __builtin_amdgcn_s_setprio(1);
#pragma unroll
    for (int t = 0; t < 2; ++t) {
      const int m = t ? (15 - w) : w;
      if (m >= 4 * j) {  // wave-uniform branch; m>>2==j is the masked diagonal
        f32x4 s[4];
#pragma unroll
        for (int n = 0; n < 4; ++n) s[n] = vzero;
        // S^T = K Q^T: A = K-frag (row-major Kj), B = Q-frag (mirror prop).
        // C layout: s_in64 = n*16 + quad*4 + rr, q_local = l15.
#pragma unroll
        for (int ks = 0; ks < 2; ++ks)
#pragma unroll
          for (int n = 0; n < 4; ++n) {
            bf16x8 kf = *(const bf16x8*)&Kj[p][n * 16 + l15][ks * 32 + quad * 8];
            s[n] = __builtin_amdgcn_mfma_f32_16x16x32_bf16(kf, qf[t][ks], s[n],
                                                           0, 0, 0);
          }
        // mask + pack 4 contiguous s-values -> b64 store (wave-private Sw,
        // intra-wave lgkmcnt ordering, no barrier)
        const int mloc = (m & 3) * 16;
        const bool diag = ((m >> 2) == j);
#pragma unroll
        for (int n = 0; n < 4; ++n) {
          bf16x4 pk;
#pragma unroll
          for (int rr = 0; rr < 4; ++rr) {
            float val = s[n][rr];
            if (diag && (n * 16 + quad * 4 + rr > mloc + l15)) val = 0.f;
            pk[rr] = (__bf16)val;
          }
          *(bf16x4*)&Sw[w][l15][n * 16 + quad * 4] = pk;
        }
#pragma unroll
        for (int ks = 0; ks < 2; ++ks) {
          bf16x8 a = *(const bf16x8*)&Sw[w][l15][ks * 32 + quad * 8];
#pragma unroll
          for (int n = 0; n < 4; ++n) {
            bf16x8 vf = *(const bf16x8*)&VTj[p][n * 16 + l15][ks * 32 + quad * 8];
            acc[t][n] =
                __builtin_amdgcn_mfma_f32_16x16x32_bf16(a, vf, acc[t][n], 0, 0, 0);
          }
        }
      }
    }
    __builtin_amdgcn_s_setprio(0);
    if (j < 3) {
      WRITEJ(p ^ 1);      // write-late into the idle buffer
      __syncthreads();    // single barrier per subtile
      if (j < 2) LOADJ(j + 2);  // issue-early next tile's loads
    }
  }

  // ---- epilogue: write O (fp32)
  float* op = out + base;
#pragma unroll
  for (int t = 0; t < 2; ++t) {
    const int m = t ? (15 - w) : w;
    const int row = m * 16 + quad * 4;
#pragma unroll
    for (int n = 0; n < 4; ++n)
#pragma unroll
      for (int rr = 0; rr < 4; ++rr)
        op[(long)(row + rr) * D_ + n * 16 + l15] = acc[t][n][rr];
  }
}

extern "C" void kernel_launch(void* const* d_in, const int* in_sizes, int n_in,
                              void* d_out, int out_size, void* d_ws, size_t ws_size,
                              hipStream_t stream) {
  const float* q = (const float*)d_in[0];
  const float* k = (const float*)d_in[1];
  const float* v = (const float*)d_in[2];
  float* out = (float*)d_out;
  float* kvws = (float*)d_ws;  // [0,8MiB): 512 x 64x64 fp32 states
  int* flags = (int*)((char*)d_ws + FLAG_OFF_BYTES);  // 512 ints

  // zero the flags each iteration (ws is poisoned by the harness); memsetAsync
  // is graph-capturable and orders before the kernel on the same stream.
  hipMemsetAsync(flags, 0, BH_ * NCH * sizeof(int), stream);
  hipLaunchKernelGGL(fused_attn_kernel, dim3(BH_ * NCH), dim3(512), 0, stream,
                     q, k, v, kvws, flags, out);
}

// Round 6
// 180.288 us; speedup vs baseline: 1.5007x; 1.5007x over previous
//
#include <hip/hip_runtime.h>
#include <hip/hip_bf16.h>

// Causal linear attention, fused single kernel with flag-based chunk handshake.
// B=4 H=16 T=2048 D=64. Chunk C=256, NC=8, BH=64. Grid 512 blocks x 512 thr
// (= exactly 2 blocks/CU co-residency capacity: LDS 63KB -> 2/CU, VGPR<=128).
//
// Phase 1: block (bh,c) computes KV_c = K_c^T V_c -> ws, then publishes a
//   per-chunk flag (block barrier -> agent-scope RELEASE store). Phase 1 has
//   NO dependencies -> producers never wait -> no deadlock given residency.
// Phase 2: consumer waits for prior-chunk flags, then
//   O = Q @ prefixKV + tril(Q K_c^T) V_c.
//
// R6 = R5 with the fence spelling fixed: __hip_atomic_fence doesn't exist on
// this ROCm; use __builtin_amdgcn_fence(__ATOMIC_ACQUIRE, "agent").
// R5 rationale vs R4 (passed but 177us): R4 had ALL 512 threads spin on
// agent-scope ACQUIRE loads -> each poll iteration emitted an L1+L2
// invalidate (per-XCD L2s aren't coherent, so agent-acquire must inv L2) ->
// ~448 spinning blocks thrashed every XCD's L2 and starved producers. Now:
// thread 0 polls RELAXED (no invalidates), then ONE acquire fence +
// __syncthreads() orders the whole block's plain state loads (L1 is per-CU,
// so thread 0's invalidate covers the block). Invalidates: thousands -> 1.

#define B_   4
#define H_   16
#define T_   2048
#define D_   64
#define BH_  64
#define CCH  256
#define NCH  8
#define LPAD 8
#define LW   (D_ + LPAD)   // 72 bf16 = 144 B row stride

#define FLAG_OFF_BYTES (8u << 20)  // ws: [0,8MiB) = 512 KV states, then flags

typedef __bf16 bf16x4 __attribute__((ext_vector_type(4)));
typedef __bf16 bf16x8 __attribute__((ext_vector_type(8)));
typedef float  f32x2  __attribute__((ext_vector_type(2)));
typedef float  f32x4  __attribute__((ext_vector_type(4)));

// MFMA 16x16x32 bf16 fragment layouts (HW-verified):
//   A: A[m = lane&15][k = (lane>>4)*8 + j]   (8 contiguous k per lane)
//   B: B[k = (lane>>4)*8 + j][n = lane&15]
//   C/D: row = (lane>>4)*4 + reg, col = lane&15
// Mirror property: row-major 8-elem load of X rows = A-frag(X) = B-frag(X^T).

__global__ __launch_bounds__(512, 4) void fused_attn_kernel(
    const float* __restrict__ q, const float* __restrict__ k,
    const float* __restrict__ v, float* __restrict__ kvws,
    int* __restrict__ flags, float* __restrict__ out) {
  __shared__ __align__(16) __bf16 KVT[D_][LW];     // KVsum^T [d2][d1]
  __shared__ __align__(16) __bf16 Kj[2][64][LW];   // ph2: K [s][d]; ph1: K^T [d][s]
  __shared__ __align__(16) __bf16 VTj[2][64][LW];  // V^T [d][s] (both phases)
  __shared__ __align__(16) __bf16 Sw[8][16][LW];   // per-wave S tile
  // 9216 + 18432 + 18432 + 18432 = 64512 B -> 2 blocks/CU

  const int tid  = threadIdx.x;
  const int lane = tid & 63;
  const int w    = tid >> 6;        // 0..7
  const int quad = lane >> 4;
  const int l15  = lane & 15;
  // XCD swizzle (perf-only): XCD = blockIdx%8 -> pin all 8 chunks of a bh to
  // one XCD so its ws states + flags are L2-local. Bijective on [0,512).
  const int bx  = blockIdx.x;
  const int bh  = (bx & 7) * 8 + ((bx >> 3) & 7);
  const int c   = bx >> 6;
  const int lin = bh * NCH + c;     // logical state index
  const long base = ((long)bh * T_ + (long)c * CCH) * D_;

  const f32x4 vzero = {0.f, 0.f, 0.f, 0.f};

  // ================= phase 1: KV_c = K_c^T V_c =================
  // staging: waves 0-3 stage K, waves 4-7 stage V (4x4 register transpose)
  const int tt  = tid & 255;
  const int s4a = tt >> 4;    // s-block of 4
  const int d4a = tt & 15;    // d-block of 4
  const int mat = tid >> 8;   // 0 = K, 1 = V (wave-uniform)
  const float* src1 = mat ? v : k;
  __bf16* dst1 = mat ? &VTj[0][0][0] : &Kj[0][0][0];
  const float* sp1 = src1 + base + (long)(s4a * 4) * D_ + d4a * 4;

  f32x4 reg1[4];
  auto LOAD1 = [&](int st) {
#pragma unroll
    for (int r = 0; r < 4; ++r)
      reg1[r] = *(const f32x4*)(sp1 + (long)(st * 64 + r) * D_);
  };
  auto WRITE1 = [&](int p) {
#pragma unroll
    for (int cc2 = 0; cc2 < 4; ++cc2) {
      bf16x4 a;
#pragma unroll
      for (int r = 0; r < 4; ++r) a[r] = (__bf16)reg1[r][cc2];
      *(bf16x4*)(dst1 + ((long)p * 64 + d4a * 4 + cc2) * LW + s4a * 4) = a;
    }
  };

  // phase-2 staging mappings + lambdas (also used for pre-wait j=0 prefetch)
  const int slK = tid >> 3;          // K: row 0..63
  const int d0K = (tid & 7) * 8;     // K: 8 cols
  const int sV  = (tid >> 5) * 4;    // V: s-block of 4
  const int dV  = (tid & 31) * 2;    // V: 2 cols

  f32x4 kreg0, kreg1;
  f32x2 vreg[4];
  auto LOADJ = [&](int j) {
    const float* kp = k + base + (long)(j * 64 + slK) * D_ + d0K;
    const float* vp = v + base + (long)(j * 64 + sV) * D_ + dV;
    kreg0 = *(const f32x4*)(kp);
    kreg1 = *(const f32x4*)(kp + 4);
#pragma unroll
    for (int r = 0; r < 4; ++r) vreg[r] = *(const f32x2*)(vp + (long)r * D_);
  };
  auto WRITEJ = [&](int p) {
    bf16x8 kb;
#pragma unroll
    for (int e = 0; e < 4; ++e) {
      kb[e]     = (__bf16)kreg0[e];
      kb[4 + e] = (__bf16)kreg1[e];
    }
    *(bf16x8*)&Kj[p][slK][d0K] = kb;
#pragma unroll
    for (int e = 0; e < 2; ++e) {
      bf16x4 va;
#pragma unroll
      for (int r = 0; r < 4; ++r) va[r] = (__bf16)vreg[r][e];
      *(bf16x4*)&VTj[p][dV + e][sV] = va;
    }
  };

  LOAD1(0);
  WRITE1(0);

  // Q A-fragments (issued early; consumed in phase 2).
  // wave w owns M-tiles {w, 15-w}: uniform 5 (j,tile) MFMA pairs per wave.
  bf16x8 qf[2][2];
#pragma unroll
  for (int t = 0; t < 2; ++t) {
    const int m = t ? (15 - w) : w;
    const float* qp = q + base + (long)(m * 16 + l15) * D_ + quad * 8;
#pragma unroll
    for (int ks = 0; ks < 2; ++ks) {
      f32x4 lo = *(const f32x4*)(qp + ks * 32);
      f32x4 hi = *(const f32x4*)(qp + ks * 32 + 4);
      bf16x8 f;
#pragma unroll
      for (int e = 0; e < 4; ++e) {
        f[e]     = (__bf16)lo[e];
        f[4 + e] = (__bf16)hi[e];
      }
      qf[t][ks] = f;
    }
  }

  __syncthreads();

  // phase-1 MFMA: wave w -> d1 rows (w&3)*16..+16, d2 cols (w>>2)*32..+32
  const int r1 = (w & 3) * 16;
  const int nb = (w >> 2) * 2;
  f32x4 acc1[2] = {vzero, vzero};
  for (int st = 0; st < 4; ++st) {
    const int p = st & 1;
    if (st < 3) LOAD1(st + 1);  // issue early
#pragma unroll
    for (int ks = 0; ks < 2; ++ks) {
      bf16x8 a = *(const bf16x8*)&Kj[p][r1 + l15][ks * 32 + quad * 8];  // K^T rows
#pragma unroll
      for (int nn = 0; nn < 2; ++nn) {
        bf16x8 b = *(const bf16x8*)&VTj[p][(nb + nn) * 16 + l15][ks * 32 + quad * 8];
        acc1[nn] = __builtin_amdgcn_mfma_f32_16x16x32_bf16(a, b, acc1[nn], 0, 0, 0);
      }
    }
    if (st < 3) {
      WRITE1(p ^ 1);
      __syncthreads();
    }
  }
  // write own chunk state. C layout: d1 = r1+quad*4+rr, d2 = col.
  {
    float* wsp = kvws + ((long)lin << 12);
#pragma unroll
    for (int nn = 0; nn < 2; ++nn)
#pragma unroll
      for (int rr = 0; rr < 4; ++rr)
        wsp[(r1 + quad * 4 + rr) * 64 + (nb + nn) * 16 + l15] = acc1[nn][rr];
  }
  // publish: all threads' ws stores are drained by the barrier (vmcnt(0)
  // before s_barrier); agent-scope release then makes them visible before
  // the flag becomes visible.
  __syncthreads();
  if (tid == 0)
    __hip_atomic_store(&flags[lin], 1, __ATOMIC_RELEASE, __HIP_MEMORY_SCOPE_AGENT);

  // prefetch phase-2 j=0 tile into region 0 (phase-1 st=3 readers use region
  // 1 -> disjoint; publish barrier already passed).
  LOADJ(0);
  WRITEJ(0);

  // ================= phase 2: attention =================
  // ---- wait for prior chunks: thread 0 polls RELAXED (no cache invalidates
  // in the spin), then ONE acquire fence (single L1/L2 invalidate) and a
  // block barrier order every thread's subsequent plain state loads.
  if (c > 0) {
    if (tid == 0) {
      for (int cc = 0; cc < c; ++cc)
        while (__hip_atomic_load(&flags[bh * NCH + cc], __ATOMIC_RELAXED,
                                 __HIP_MEMORY_SCOPE_AGENT) == 0)
          __builtin_amdgcn_s_sleep(2);
      __builtin_amdgcn_fence(__ATOMIC_ACQUIRE, "agent");
    }
    __syncthreads();
  }

  // ---- prefix-sum KV states of prior chunks -> KVT (bf16, transposed)
  float kvacc[8];
#pragma unroll
  for (int i = 0; i < 8; ++i) kvacc[i] = 0.f;
  const float* wsbh = kvws + ((long)(bh * NCH) << 12);
  for (int cc = 0; cc < c; ++cc) {
    const float* pp = wsbh + ((long)cc << 12) + tid * 8;
#pragma unroll
    for (int x = 0; x < 2; ++x) {
      f32x4 t2 = *(const f32x4*)(pp + x * 4);
#pragma unroll
      for (int e = 0; e < 4; ++e) kvacc[x * 4 + e] += t2[e];
    }
  }
  {
    const int d1  = tid >> 3;          // lin8 = tid*8+ii: d1 = lin8>>6
    const int d2b = (tid & 7) * 8;     //                  d2 = d2b+ii
#pragma unroll
    for (int ii = 0; ii < 8; ++ii) KVT[d2b + ii][d1] = (__bf16)kvacc[ii];
  }

  f32x4 acc[2][4];
#pragma unroll
  for (int t = 0; t < 2; ++t)
#pragma unroll
    for (int n = 0; n < 4; ++n) acc[t][n] = vzero;

  LOADJ(1);         // prefetch j=1 under the inter-chunk matmul
  __syncthreads();  // KVT + j=0 tile ready

  // ---- inter-chunk: O += Q @ KVsum (zeros when c==0; uniform work)
#pragma unroll
  for (int ks = 0; ks < 2; ++ks)
#pragma unroll
    for (int n = 0; n < 4; ++n) {
      bf16x8 b = *(const bf16x8*)&KVT[n * 16 + l15][ks * 32 + quad * 8];
#pragma unroll
      for (int t = 0; t < 2; ++t)
        acc[t][n] =
            __builtin_amdgcn_mfma_f32_16x16x32_bf16(qf[t][ks], b, acc[t][n], 0, 0, 0);
    }

  // ---- intra-chunk causal part over 4 key subtiles of 64
  for (int j = 0; j < 4; ++j) {
    const int p = j & 1;
    __builtin_amdgcn_s_setprio(1);
#pragma unroll
    for (int t = 0; t < 2; ++t) {
      const int m = t ? (15 - w) : w;
      if (m >= 4 * j) {  // wave-uniform branch; m>>2==j is the masked diagonal
        f32x4 s[4];
#pragma unroll
        for (int n = 0; n < 4; ++n) s[n] = vzero;
        // S^T = K Q^T: A = K-frag (row-major Kj), B = Q-frag (mirror prop).
        // C layout: s_in64 = n*16 + quad*4 + rr, q_local = l15.
#pragma unroll
        for (int ks = 0; ks < 2; ++ks)
#pragma unroll
          for (int n = 0; n < 4; ++n) {
            bf16x8 kf = *(const bf16x8*)&Kj[p][n * 16 + l15][ks * 32 + quad * 8];
            s[n] = __builtin_amdgcn_mfma_f32_16x16x32_bf16(kf, qf[t][ks], s[n],
                                                           0, 0, 0);
          }
        // mask + pack 4 contiguous s-values -> b64 store (wave-private Sw,
        // intra-wave lgkmcnt ordering, no barrier)
        const int mloc = (m & 3) * 16;
        const bool diag = ((m >> 2) == j);
#pragma unroll
        for (int n = 0; n < 4; ++n) {
          bf16x4 pk;
#pragma unroll
          for (int rr = 0; rr < 4; ++rr) {
            float val = s[n][rr];
            if (diag && (n * 16 + quad * 4 + rr > mloc + l15)) val = 0.f;
            pk[rr] = (__bf16)val;
          }
          *(bf16x4*)&Sw[w][l15][n * 16 + quad * 4] = pk;
        }
#pragma unroll
        for (int ks = 0; ks < 2; ++ks) {
          bf16x8 a = *(const bf16x8*)&Sw[w][l15][ks * 32 + quad * 8];
#pragma unroll
          for (int n = 0; n < 4; ++n) {
            bf16x8 vf = *(const bf16x8*)&VTj[p][n * 16 + l15][ks * 32 + quad * 8];
            acc[t][n] =
                __builtin_amdgcn_mfma_f32_16x16x32_bf16(a, vf, acc[t][n], 0, 0, 0);
          }
        }
      }
    }
    __builtin_amdgcn_s_setprio(0);
    if (j < 3) {
      WRITEJ(p ^ 1);      // write-late into the idle buffer
      __syncthreads();    // single barrier per subtile
      if (j < 2) LOADJ(j + 2);  // issue-early next tile's loads
    }
  }

  // ---- epilogue: write O (fp32)
  float* op = out + base;
#pragma unroll
  for (int t = 0; t < 2; ++t) {
    const int m = t ? (15 - w) : w;
    const int row = m * 16 + quad * 4;
#pragma unroll
    for (int n = 0; n < 4; ++n)
#pragma unroll
      for (int rr = 0; rr < 4; ++rr)
        op[(long)(row + rr) * D_ + n * 16 + l15] = acc[t][n][rr];
  }
}

extern "C" void kernel_launch(void* const* d_in, const int* in_sizes, int n_in,
                              void* d_out, int out_size, void* d_ws, size_t ws_size,
                              hipStream_t stream) {
  const float* q = (const float*)d_in[0];
  const float* k = (const float*)d_in[1];
  const float* v = (const float*)d_in[2];
  float* out = (float*)d_out;
  float* kvws = (float*)d_ws;  // [0,8MiB): 512 x 64x64 fp32 states
  int* flags = (int*)((char*)d_ws + FLAG_OFF_BYTES);  // 512 ints

  // zero the flags each iteration (ws is poisoned by the harness); memsetAsync
  // is graph-capturable and orders before the kernel on the same stream.
  (void)hipMemsetAsync(flags, 0, BH_ * NCH * sizeof(int), stream);
  hipLaunchKernelGGL(fused_attn_kernel, dim3(BH_ * NCH), dim3(512), 0, stream,
                     q, k, v, kvws, flags, out);
}

// Round 7
// 145.351 us; speedup vs baseline: 1.8615x; 1.2404x over previous
//
#include <hip/hip_runtime.h>
#include <hip/hip_bf16.h>

// Causal linear attention, chunked decomposition (two kernels — the fused
// flag-handshake variant measured 83us/dispatch vs ~50us for this split; the
// wait-skew + agent-acquire L2 invalidates made fusion net-negative).
// B=4 H=16 T=2048 D=64. Chunk C=256, NC=8 chunks, BH=64 batch-heads.
// Kernel 1: per-(bh,chunk) KV state  KV_c = K_c^T V_c  (64x64 fp32) -> ws
// Kernel 2: per-(bh,chunk) output    O = Q_c * prefixKV + tril(Q_c K_c^T) V_c
// bf16 MFMA (16x16x32), fp32 accumulate. Threshold 36.96 >> bf16 error (~3).
//
// R7 = R1 (best measured, 143.66us) + two attn-kernel tweaks:
//  - j=0 K/V staging loads + Q loads issued BEFORE the prefix-sum loop, so
//    the three serial global-latency ramps at block start (prefix chain, Q,
//    j0 staging) overlap instead of running back-to-back.
//  - c==0 blocks skip prefix/KVT/inter-chunk entirely (block-uniform branch).
// Structure otherwise identical to R1: S^T via swapped MFMA operands
// (wave-private Sw, no barriers around it), vectorized LDS staging, dbuf +
// issue-early/write-late, 1 barrier per key subtile.

#define B_   4
#define H_   16
#define T_   2048
#define D_   64
#define BH_  64
#define CCH  256
#define NCH  8
#define LPAD 8
#define LW   (D_ + LPAD)   // 72 bf16 = 144 B row stride (16B aligned)

typedef __bf16 bf16x4 __attribute__((ext_vector_type(4)));
typedef __bf16 bf16x8 __attribute__((ext_vector_type(8)));
typedef float  f32x4  __attribute__((ext_vector_type(4)));

// MFMA fragment layouts (16x16x32 bf16, HW-verified per guide):
//   A: A[m = lane&15][k = (lane>>4)*8 + j]   (8 contiguous k per lane)
//   B: B[k = (lane>>4)*8 + j][n = lane&15]
//   C/D: row = (lane>>4)*4 + reg, col = lane&15
// Mirror property: a row-major contiguous 8-elem load of X rows is both the
// A-fragment of X and the B-fragment of X^T.

__global__ __launch_bounds__(256, 2) void kv_chunk_kernel(
    const float* __restrict__ k, const float* __restrict__ v,
    float* __restrict__ kvws) {
  __shared__ __align__(16) __bf16 KT[2][D_][LW];  // [d][s] transposed, dbuf
  __shared__ __align__(16) __bf16 VT[2][D_][LW];  // [d][s] transposed, dbuf

  const int tid  = threadIdx.x;
  const int lane = tid & 63;
  const int w    = tid >> 6;
  const int quad = lane >> 4;
  const int l15  = lane & 15;
  const int bh   = blockIdx.x >> 3;
  const int c    = blockIdx.x & (NCH - 1);
  const long base = ((long)bh * T_ + (long)c * CCH) * D_;

  // 4x4 register-transpose staging: thread (s4,d4) owns a 4x4 tile.
  const int s4 = tid >> 4;   // 0..15 -> s-block of 4
  const int d4 = tid & 15;   // 0..15 -> d-block of 4

  f32x4 kreg[4], vreg[4];
  const float* kp0 = k + base + (long)(s4 * 4) * D_ + d4 * 4;
  const float* vp0 = v + base + (long)(s4 * 4) * D_ + d4 * 4;

  auto LOAD = [&](int st) {
#pragma unroll
    for (int r = 0; r < 4; ++r) {
      kreg[r] = *(const f32x4*)(kp0 + (long)(st * 64 + r) * D_);
      vreg[r] = *(const f32x4*)(vp0 + (long)(st * 64 + r) * D_);
    }
  };
  auto WRITE = [&](int p) {
#pragma unroll
    for (int cc2 = 0; cc2 < 4; ++cc2) {
      bf16x4 ka, va;
#pragma unroll
      for (int r = 0; r < 4; ++r) {
        ka[r] = (__bf16)kreg[r][cc2];
        va[r] = (__bf16)vreg[r][cc2];
      }
      *(bf16x4*)&KT[p][d4 * 4 + cc2][s4 * 4] = ka;
      *(bf16x4*)&VT[p][d4 * 4 + cc2][s4 * 4] = va;
    }
  };

  const f32x4 vzero = {0.f, 0.f, 0.f, 0.f};
  f32x4 acc[4];
#pragma unroll
  for (int n = 0; n < 4; ++n) acc[n] = vzero;

  LOAD(0);
  WRITE(0);
  __syncthreads();
  for (int st = 0; st < 4; ++st) {  // 4 s-tiles of 64 cover the 256 chunk
    const int p = st & 1;
    if (st < 3) LOAD(st + 1);  // issue early; write after compute
    // KV[d1][d2] += sum_s K[s][d1]*V[s][d2]; wave w owns d1 rows [16w,16w+16)
#pragma unroll
    for (int ks = 0; ks < 2; ++ks) {
      bf16x8 a = *(const bf16x8*)&KT[p][w * 16 + l15][ks * 32 + quad * 8];
#pragma unroll
      for (int n = 0; n < 4; ++n) {
        bf16x8 b = *(const bf16x8*)&VT[p][n * 16 + l15][ks * 32 + quad * 8];
        acc[n] = __builtin_amdgcn_mfma_f32_16x16x32_bf16(a, b, acc[n], 0, 0, 0);
      }
    }
    if (st < 3) {
      WRITE(p ^ 1);
      __syncthreads();
    }
  }
  float* out = kvws + ((long)blockIdx.x << 12);  // 64*64 fp32 per (bh,c)
#pragma unroll
  for (int n = 0; n < 4; ++n)
#pragma unroll
    for (int rr = 0; rr < 4; ++rr)
      out[(w * 16 + quad * 4 + rr) * 64 + n * 16 + l15] = acc[n][rr];
}

__global__ __launch_bounds__(256, 2) void attn_chunk_kernel(
    const float* __restrict__ q, const float* __restrict__ k,
    const float* __restrict__ v, const float* __restrict__ kvws,
    float* __restrict__ out) {
  __shared__ __align__(16) __bf16 KVT[D_][LW];     // KVsum transposed [d2][d1]
  __shared__ __align__(16) __bf16 Kj[2][64][LW];   // key subtile [s][d], dbuf
  __shared__ __align__(16) __bf16 VTj[2][D_][LW];  // value subtile [d][s], dbuf
  __shared__ __align__(16) __bf16 Sw[4][16][LW];   // per-wave S tile [m][s]

  const int tid  = threadIdx.x;
  const int lane = tid & 63;
  const int w    = tid >> 6;
  const int quad = lane >> 4;
  const int l15  = lane & 15;
  const int bh   = blockIdx.x >> 3;
  const int c    = blockIdx.x & (NCH - 1);
  const long base = ((long)bh * T_ + (long)c * CCH) * D_;

  // staging thread mappings
  const int slK = tid >> 2;          // K: one row per thread
  const int d0K = (tid & 3) * 16;    // K: 16 cols per thread
  const int s4  = tid >> 4;          // V: 4x4 tile, s-block
  const int d4  = tid & 15;          // V: 4x4 tile, d-block

  f32x4 kreg[4], vreg[4];
  auto LOADJ = [&](int j) {
    const float* kp = k + base + (long)(j * 64 + slK) * D_ + d0K;
    const float* vp = v + base + (long)(j * 64 + s4 * 4) * D_ + d4 * 4;
#pragma unroll
    for (int r = 0; r < 4; ++r) kreg[r] = *(const f32x4*)(kp + r * 4);
#pragma unroll
    for (int r = 0; r < 4; ++r) vreg[r] = *(const f32x4*)(vp + (long)r * D_);
  };
  auto WRITEJ = [&](int p) {
    bf16x8 kb0, kb1;
#pragma unroll
    for (int e = 0; e < 4; ++e) {
      kb0[e]     = (__bf16)kreg[0][e];
      kb0[4 + e] = (__bf16)kreg[1][e];
      kb1[e]     = (__bf16)kreg[2][e];
      kb1[4 + e] = (__bf16)kreg[3][e];
    }
    *(bf16x8*)&Kj[p][slK][d0K]     = kb0;
    *(bf16x8*)&Kj[p][slK][d0K + 8] = kb1;
#pragma unroll
    for (int cc2 = 0; cc2 < 4; ++cc2) {
      bf16x4 va;
#pragma unroll
      for (int r = 0; r < 4; ++r) va[r] = (__bf16)vreg[r][cc2];
      *(bf16x4*)&VTj[p][d4 * 4 + cc2][s4 * 4] = va;
    }
  };

  // ---- 0. issue j=0 staging loads + Q loads FIRST: their HBM/L3 latency
  // overlaps the prefix-sum chain below (independent register targets).
  LOADJ(0);

  bf16x8 qf[4][2];
#pragma unroll
  for (int i = 0; i < 4; ++i) {
    int row = (w + 4 * i) * 16 + l15;
    const float* qp = q + base + (long)row * D_ + quad * 8;
#pragma unroll
    for (int ks = 0; ks < 2; ++ks) {
      f32x4 lo = *(const f32x4*)(qp + ks * 32);
      f32x4 hi = *(const f32x4*)(qp + ks * 32 + 4);
      bf16x8 f;
#pragma unroll
      for (int e = 0; e < 4; ++e) {
        f[e]     = (__bf16)lo[e];
        f[4 + e] = (__bf16)hi[e];
      }
      qf[i][ks] = f;
    }
  }

  // ---- 1. prefix-sum KV states of prior chunks -> KVT (bf16, transposed)
  // (skipped entirely for c==0: KVT is never read there)
  if (c > 0) {
    float kvacc[16];
#pragma unroll
    for (int i = 0; i < 16; ++i) kvacc[i] = 0.f;
    const float* wsbh = kvws + ((long)(bh * NCH) << 12);
    for (int cc = 0; cc < c; ++cc) {
      const float* pp = wsbh + ((long)cc << 12) + tid * 16;
#pragma unroll
      for (int x = 0; x < 4; ++x) {
        f32x4 t = *(const f32x4*)(pp + x * 4);
#pragma unroll
        for (int e = 0; e < 4; ++e) kvacc[x * 4 + e] += t[e];
      }
    }
    const int d1  = tid >> 2;          // lin = tid*16+ii: d1 = lin>>6
    const int d2b = (tid & 3) * 16;    //                  d2 = d2b+ii
#pragma unroll
    for (int ii = 0; ii < 16; ++ii) KVT[d2b + ii][d1] = (__bf16)kvacc[ii];
  }

  // ---- 2. stage j=0 tile (loads from step 0 have returned by now)
  WRITEJ(0);

  const f32x4 vzero = {0.f, 0.f, 0.f, 0.f};
  f32x4 acc[4][4];
#pragma unroll
  for (int i = 0; i < 4; ++i)
#pragma unroll
    for (int n = 0; n < 4; ++n) acc[i][n] = vzero;

  LOADJ(1);         // prefetch j=1 under the inter-chunk matmul
  __syncthreads();  // KVT + j=0 tile visible to all waves

  // ---- 3. inter-chunk: O += Q @ KVsum (c==0: acc stays zero)
  if (c > 0) {
#pragma unroll
    for (int ks = 0; ks < 2; ++ks)
#pragma unroll
      for (int n = 0; n < 4; ++n) {
        bf16x8 b = *(const bf16x8*)&KVT[n * 16 + l15][ks * 32 + quad * 8];
#pragma unroll
        for (int i = 0; i < 4; ++i)
          acc[i][n] =
              __builtin_amdgcn_mfma_f32_16x16x32_bf16(qf[i][ks], b, acc[i][n], 0, 0, 0);
      }
  }

  // ---- 4. intra-chunk causal part over 4 key subtiles of 64
  for (int j = 0; j < 4; ++j) {
    const int p = j & 1;
    // M-tile (w+4i) needs key subtile j iff i >= j; i==j is the masked diagonal.
    for (int i = j; i < 4; ++i) {  // uniform trip count across waves
      f32x4 s[4];
#pragma unroll
      for (int n = 0; n < 4; ++n) s[n] = vzero;
      // S^T = K Q^T: A = K-frag (row-major Kj), B = Q-frag (mirror property).
      // C layout: s_in64 = n*16 + quad*4 + rr, q_local = l15.
#pragma unroll
      for (int ks = 0; ks < 2; ++ks) {
#pragma unroll
        for (int n = 0; n < 4; ++n) {
          bf16x8 kf = *(const bf16x8*)&Kj[p][n * 16 + l15][ks * 32 + quad * 8];
          s[n] = __builtin_amdgcn_mfma_f32_16x16x32_bf16(kf, qf[i][ks], s[n], 0, 0, 0);
        }
      }
      // mask + pack 4 contiguous s-values -> one b64 store per n (wave-private
      // Sw: no block barrier needed, intra-wave LDS ordering suffices).
#pragma unroll
      for (int n = 0; n < 4; ++n) {
        bf16x4 pk;
#pragma unroll
        for (int rr = 0; rr < 4; ++rr) {
          float val = s[n][rr];
          if (i == j && (n * 16 + quad * 4 + rr > 16 * w + l15)) val = 0.f;
          pk[rr] = (__bf16)val;
        }
        *(bf16x4*)&Sw[w][l15][n * 16 + quad * 4] = pk;
      }
#pragma unroll
      for (int ks = 0; ks < 2; ++ks) {
        bf16x8 a = *(const bf16x8*)&Sw[w][l15][ks * 32 + quad * 8];
#pragma unroll
        for (int n = 0; n < 4; ++n) {
          bf16x8 vf = *(const bf16x8*)&VTj[p][n * 16 + l15][ks * 32 + quad * 8];
          acc[i][n] =
              __builtin_amdgcn_mfma_f32_16x16x32_bf16(a, vf, acc[i][n], 0, 0, 0);
        }
      }
    }
    if (j < 3) {
      WRITEJ(p ^ 1);      // write-late into the idle buffer
      __syncthreads();    // single barrier per subtile
      if (j < 2) LOADJ(j + 2);  // issue-early next tile's loads
    }
  }

  // ---- 5. epilogue: write O (fp32)
  float* op = out + base;
#pragma unroll
  for (int i = 0; i < 4; ++i) {
    int row = (w + 4 * i) * 16 + quad * 4;
#pragma unroll
    for (int n = 0; n < 4; ++n)
#pragma unroll
      for (int rr = 0; rr < 4; ++rr)
        op[(long)(row + rr) * D_ + n * 16 + l15] = acc[i][n][rr];
  }
}

extern "C" void kernel_launch(void* const* d_in, const int* in_sizes, int n_in,
                              void* d_out, int out_size, void* d_ws, size_t ws_size,
                              hipStream_t stream) {
  const float* q = (const float*)d_in[0];
  const float* k = (const float*)d_in[1];
  const float* v = (const float*)d_in[2];
  float* out = (float*)d_out;
  float* kvws = (float*)d_ws;  // needs BH_*NCH*64*64*4 = 8 MiB

  hipLaunchKernelGGL(kv_chunk_kernel, dim3(BH_ * NCH), dim3(256), 0, stream,
                     k, v, kvws);
  hipLaunchKernelGGL(attn_chunk_kernel, dim3(BH_ * NCH), dim3(256), 0, stream,
                     q, k, v, kvws, out);
}